// Round 15
// baseline (124.513 us; speedup 1.0000x reference)
//
#include <hip/hip_runtime.h>
#include <math.h>

#define NRES 768
#define CDIM 384
#define HEADS 12
#define SCALE 0.17677669529663687f  // 1/sqrt(32)

typedef _Float16 f16;
typedef _Float16 __attribute__((ext_vector_type(8))) f16x8;
typedef float __attribute__((ext_vector_type(4))) f32x4;

__device__ __forceinline__ f16x8 ldcvt8(const float* __restrict__ p) {
  float4 a = *(const float4*)p;
  float4 b = *(const float4*)(p + 4);
  f16x8 r = {(f16)a.x, (f16)a.y, (f16)a.z, (f16)a.w,
             (f16)b.x, (f16)b.y, (f16)b.z, (f16)b.w};
  return r;
}

// 4-wave (256-thr) MFMA step, used by final_gemm
__device__ __forceinline__ void mfma_step(f16 (*As)[64], f16 (*Bs)[64],
                                          int w, int lg, int lr, f32x4* acc) {
#pragma unroll
  for (int ks = 0; ks < 2; ++ks) {
    f16x8 af = *(const f16x8*)&As[w * 16 + lr][((ks * 4 + lg) ^ (lr & 7)) * 8];
#pragma unroll
    for (int c = 0; c < 4; ++c) {
      f16x8 bf = *(const f16x8*)&Bs[c * 16 + lr][((ks * 4 + lg) ^ (lr & 7)) * 8];
      acc[c] = __builtin_amdgcn_mfma_f32_16x16x32_f16(af, bf, acc[c], 0, 0, 0);
    }
  }
}

// ---------------- K1: role-split mega kernel (512 thr) ----------------
// bid<576:        pair-bias stream via global_load_lds DMA pipeline -> biasb (fp16)
// 576<=bid<876:   S16[768x1584] = f16(single * Wcat^T + bcat)
// 876<=bid<894:   Wcomb[384x192] = Wo * [Wpo | bpo | 0]^T
__global__ __launch_bounds__(512) void k1_mega(
    const float* __restrict__ pair, const float* __restrict__ Wpb, const float* __restrict__ bpb,
    const float* __restrict__ single,
    const float* __restrict__ Wq, const float* __restrict__ Wk, const float* __restrict__ Wv,
    const float* __restrict__ Wqp, const float* __restrict__ Wkp, const float* __restrict__ Wvp,
    const float* __restrict__ bq, const float* __restrict__ bk, const float* __restrict__ bv,
    const float* __restrict__ bqp, const float* __restrict__ bkp, const float* __restrict__ bvp,
    const float* __restrict__ Wpo, const float* __restrict__ bpo, const float* __restrict__ Wo,
    f16* __restrict__ biasb, f16* __restrict__ Wcomb, f16* __restrict__ S16) {
  __shared__ f16 smem[30304];   // 60.6 KB: bias_l 13920 f16 + 8 waves x 4 KB DMA
  const int bid = blockIdx.x;
  const int t = threadIdx.x;
  const int w = t >> 6, l = t & 63;
  const int lg = l >> 4, lr = l & 15;
  const f16 z0 = (f16)0.f;

  if (bid < 576) {
    f16* bias_l = smem;                        // [12][1160] f16
    f16* dmaw = smem + 13920 + w * 2048;       // wave-private 4 KB (2 x 2 KB buffers)
    const float* bpf = (const float*)dmaw;     // fp32 read view of DMA buffers
    const int mblk = bid % 12;
    const int q0 = (bid / 12) * 16;
    const int m0 = mblk * 64;

    f16x8 bfr[4];
#pragma unroll
    for (int ks = 0; ks < 4; ++ks)
#pragma unroll
      for (int j = 0; j < 8; ++j)
        bfr[ks][j] = (f16)((lr < HEADS) ? Wpb[lr * 128 + ks * 32 + lg * 8 + j] : 0.f);
    const float bh = (lr < HEADS) ? bpb[lr] : 0.f;

    const int pos0 = l >> 3;   // 0..7 (position sub-index for DMA source)
    const int j7 = l & 7;      // stored 16B slot within position

    // chunk c = g8*4+ks : one ks-slice (16 pos x 32 floats, source-swizzled by 4*pos floats)
    auto issue = [&](int c) {
      const int g8 = c >> 2, ks = c & 3, buf = c & 1;
#pragma unroll
      for (int ii = 0; ii < 2; ++ii) {
        const int pos = ii * 8 + pos0;
        const int rowf = w * 128 + g8 * 16 + pos;
        const float* src = pair
            + (((size_t)(q0 + (rowf >> 6))) * NRES + (m0 + (rowf & 63))) * 128
            + ks * 32 + (((j7 - pos) & 7) << 2);
        __builtin_amdgcn_global_load_lds(
            (const __attribute__((address_space(1))) unsigned int*)src,
            (__attribute__((address_space(3))) unsigned int*)(dmaw + buf * 1024 + ii * 512),
            16, 0, 0);
      }
    };

    issue(0); issue(1);
    const int s0 = (lg * 8 + lr * 4) & 31;
    const int s1 = (s0 + 4) & 31;
#pragma unroll
    for (int g8 = 0; g8 < 8; ++g8) {
      f32x4 acc = {0.f, 0.f, 0.f, 0.f};
#pragma unroll
      for (int ks = 0; ks < 4; ++ks) {
        const int c = g8 * 4 + ks;
        if (c < 31) asm volatile("s_waitcnt vmcnt(2)" ::: "memory");
        else        asm volatile("s_waitcnt vmcnt(0)" ::: "memory");
        const float* bp = bpf + (c & 1) * 512;          // 512 floats per buffer
        float4 x0 = *(const float4*)(bp + lr * 32 + s0);
        float4 x1 = *(const float4*)(bp + lr * 32 + s1);
        f16x8 af = {(f16)x0.x, (f16)x0.y, (f16)x0.z, (f16)x0.w,
                    (f16)x1.x, (f16)x1.y, (f16)x1.z, (f16)x1.w};
        acc = __builtin_amdgcn_mfma_f32_16x16x32_f16(af, bfr[ks], acc, 0, 0, 0);
        if (c + 2 < 32) issue(c + 2);
      }
      if (lr < HEADS) {
#pragma unroll
        for (int r = 0; r < 4; ++r) {
          int rowo = (w * 8 + g8) * 16 + lg * 4 + r;
          bias_l[lr * 1160 + (rowo >> 6) * 72 + (rowo & 63)] = (f16)(acc[r] + bh);
        }
      }
    }
    __syncthreads();
    for (int i = t; i < 12 * 16 * 8; i += 512) {
      int h = i >> 7;
      int rem = i & 127;
      int row = rem >> 3, c8 = rem & 7;
      *(f16x8*)(biasb + (size_t)h * (NRES * NRES) + (size_t)(q0 + row) * NRES + m0 + c8 * 8) =
          *(const f16x8*)&smem[h * 1160 + row * 72 + c8 * 8];
    }
    return;
  }

  f16 (*As)[64] = (f16(*)[64])smem;
  f16 (*Bs)[64] = (f16(*)[64])(smem + 4096);
  const int wm = w & 3, wn = w >> 2;
  f32x4 acc[2] = {{0.f,0.f,0.f,0.f},{0.f,0.f,0.f,0.f}};

  if (bid < 876) {
    const int i = bid - 576;
    const int bm = (i / 25) * 64, bn = (i % 25) * 64;
    for (int k0 = 0; k0 < 384; k0 += 64) {
      __syncthreads();
      {
        int row = t >> 3, k8 = t & 7;
        int sw = (k8 ^ (row & 7)) * 8;
        *(f16x8*)&As[row][sw] = ldcvt8(single + (size_t)(bm + row) * 384 + k0 + k8 * 8);
        int o = bn + row;
        const float* bsrc;
        if (o < 384)       bsrc = Wq  + (size_t)o * 384;
        else if (o < 768)  bsrc = Wk  + (size_t)(o - 384) * 384;
        else if (o < 1152) bsrc = Wv  + (size_t)(o - 768) * 384;
        else if (o < 1296) bsrc = Wqp + (size_t)(o - 1152) * 384;
        else if (o < 1440) bsrc = Wkp + (size_t)(o - 1296) * 384;
        else if (o < 1584) bsrc = Wvp + (size_t)(o - 1440) * 384;
        else               bsrc = nullptr;
        f16x8 vb8 = {z0, z0, z0, z0, z0, z0, z0, z0};
        if (bsrc) vb8 = ldcvt8(bsrc + k0 + k8 * 8);
        *(f16x8*)&Bs[row][sw] = vb8;
      }
      __syncthreads();
#pragma unroll
      for (int ks = 0; ks < 2; ++ks) {
        f16x8 af = *(const f16x8*)&As[wm * 16 + lr][((ks * 4 + lg) ^ (lr & 7)) * 8];
#pragma unroll
        for (int j = 0; j < 2; ++j) {
          f16x8 bf = *(const f16x8*)&Bs[(wn * 2 + j) * 16 + lr][((ks * 4 + lg) ^ (lr & 7)) * 8];
          acc[j] = __builtin_amdgcn_mfma_f32_16x16x32_f16(af, bf, acc[j], 0, 0, 0);
        }
      }
    }
#pragma unroll
    for (int j = 0; j < 2; ++j) {
      int col = bn + (wn * 2 + j) * 16 + lr;
      if (col >= 1584) continue;
      float bb;
      if (col < 384)       bb = bq[col];
      else if (col < 768)  bb = bk[col - 384];
      else if (col < 1152) bb = bv[col - 768];
      else if (col < 1296) bb = bqp[col - 1152];
      else if (col < 1440) bb = bkp[col - 1296];
      else                 bb = bvp[col - 1440];
#pragma unroll
      for (int r = 0; r < 4; ++r) {
        int row = bm + wm * 16 + lg * 4 + r;
        S16[(size_t)row * 1584 + col] = (f16)(acc[j][r] + bb);
      }
    }
  } else {
    const int i = bid - 876;
    const int bm = (i / 3) * 64, bn = (i % 3) * 64;
    for (int k0 = 0; k0 < 384; k0 += 64) {
      __syncthreads();
      {
        int row = t >> 3, k8 = t & 7;
        int sw = (k8 ^ (row & 7)) * 8;
        *(f16x8*)&As[row][sw] = ldcvt8(Wo + (size_t)(bm + row) * 384 + k0 + k8 * 8);
        int pr = bn + row;
        f16x8 vb8 = {z0, z0, z0, z0, z0, z0, z0, z0};
        if (pr < 144) {
#pragma unroll
          for (int j = 0; j < 8; ++j) vb8[j] = (f16)Wpo[(size_t)(k0 + k8 * 8 + j) * 144 + pr];
        } else if (pr == 144) {
#pragma unroll
          for (int j = 0; j < 8; ++j) vb8[j] = (f16)bpo[k0 + k8 * 8 + j];
        }
        *(f16x8*)&Bs[row][sw] = vb8;
      }
      __syncthreads();
#pragma unroll
      for (int ks = 0; ks < 2; ++ks) {
        f16x8 af = *(const f16x8*)&As[wm * 16 + lr][((ks * 4 + lg) ^ (lr & 7)) * 8];
#pragma unroll
        for (int j = 0; j < 2; ++j) {
          f16x8 bf = *(const f16x8*)&Bs[(wn * 2 + j) * 16 + lr][((ks * 4 + lg) ^ (lr & 7)) * 8];
          acc[j] = __builtin_amdgcn_mfma_f32_16x16x32_f16(af, bf, acc[j], 0, 0, 0);
        }
      }
    }
#pragma unroll
    for (int j = 0; j < 2; ++j) {
      int col = bn + (wn * 2 + j) * 16 + lr;
      if (col >= 192) continue;
#pragma unroll
      for (int r = 0; r < 4; ++r)
        Wcomb[(size_t)(bm + wm * 16 + lg * 4 + r) * 192 + col] = (f16)acc[j][r];
    }
  }
}

// ---------------- final output GEMM: xb = attn_cat * [Wo | Wcomb]^T + bo + single ----------------
__global__ __launch_bounds__(256) void final_gemm(
    const f16* __restrict__ attn_cat, const float* __restrict__ Wo,
    const f16* __restrict__ Wcomb, const float* __restrict__ bo,
    const float* __restrict__ single, float* __restrict__ xb) {
  __shared__ f16 As[64][64];
  __shared__ f16 Bs[64][64];
  const int t = threadIdx.x;
  const int w = t >> 6, l = t & 63;
  const int lg = l >> 4, lr = l & 15;
  const int bm = blockIdx.y * 64, bn = blockIdx.x * 64;
  f32x4 acc[4] = {{0.f,0.f,0.f,0.f},{0.f,0.f,0.f,0.f},{0.f,0.f,0.f,0.f},{0.f,0.f,0.f,0.f}};
  for (int k0 = 0; k0 < 576; k0 += 64) {
    __syncthreads();
#pragma unroll
    for (int cc = 0; cc < 2; ++cc) {
      int c = t + cc * 256;
      int row = c >> 3, k8 = c & 7;
      int sw = (k8 ^ (row & 7)) * 8;
      *(f16x8*)&As[row][sw] = *(const f16x8*)(attn_cat + (size_t)(bm + row) * 576 + k0 + k8 * 8);
      f16x8 vb8;
      if (k0 < 384) vb8 = ldcvt8(Wo + (size_t)(bn + row) * 384 + k0 + k8 * 8);
      else          vb8 = *(const f16x8*)(Wcomb + (size_t)(bn + row) * 192 + (k0 - 384) + k8 * 8);
      *(f16x8*)&Bs[row][sw] = vb8;
    }
    __syncthreads();
    mfma_step(As, Bs, w, lg, lr, acc);
  }
#pragma unroll
  for (int c = 0; c < 4; ++c) {
    int col = bn + c * 16 + lr;
    float bb = bo[col];
#pragma unroll
    for (int r = 0; r < 4; ++r) {
      int row = bm + w * 16 + lg * 4 + r;
      xb[(size_t)row * 384 + col] = acc[c][r] + bb + single[(size_t)row * 384 + col];
    }
  }
}

// ---------------- rotate points, build packed fp16 features ----------------
__global__ __launch_bounds__(64) void rot_feats3(
    const f16* __restrict__ S16, const float* __restrict__ rot, const float* __restrict__ trans,
    f16* __restrict__ qf, f16* __restrict__ kf, f16* __restrict__ vfT) {
  const int n = blockIdx.x * 64 + threadIdx.x;
  const int h = blockIdx.y;
  const f16* Sr = S16 + (size_t)n * 1584;
  float R[9], T[3];
#pragma unroll
  for (int i = 0; i < 9; ++i) R[i] = rot[n * 9 + i];
#pragma unroll
  for (int i = 0; i < 3; ++i) T[i] = trans[n * 3 + i];
  f16 qh[64], kh[64];
  f16x8 qv4[4], kv4[4], vv4[4];
#pragma unroll
  for (int j = 0; j < 4; ++j) {
    qv4[j] = *(const f16x8*)(Sr + h * 32 + j * 8);
    kv4[j] = *(const f16x8*)(Sr + 384 + h * 32 + j * 8);
    vv4[j] = *(const f16x8*)(Sr + 768 + h * 32 + j * 8);
  }
#pragma unroll
  for (int c = 0; c < 32; ++c) {
    qh[c] = (f16)(SCALE * (float)qv4[c >> 3][c & 7]);
    vfT[((size_t)(h * 48 + c)) * NRES + n] = vv4[c >> 3][c & 7];
  }
#pragma unroll
  for (int j = 0; j < 4; ++j) *(f16x8*)&kh[j * 8] = kv4[j];
  float qp[12], kp[12], vp[12];
#pragma unroll
  for (int e = 0; e < 12; ++e) {
    qp[e] = (float)Sr[1152 + h * 12 + e];
    kp[e] = (float)Sr[1296 + h * 12 + e];
    vp[e] = (float)Sr[1440 + h * 12 + e];
  }
  float q2 = 0.f, k2 = 0.f;
#pragma unroll
  for (int p = 0; p < 4; ++p) {
#pragma unroll
    for (int e = 0; e < 3; ++e) {
      float qg = qp[p*3+0] * R[e] + qp[p*3+1] * R[3+e] + qp[p*3+2] * R[6+e] + T[e];
      float kg = kp[p*3+0] * R[e] + kp[p*3+1] * R[3+e] + kp[p*3+2] * R[6+e] + T[e];
      float vg = vp[p*3+0] * R[e] + vp[p*3+1] * R[3+e] + vp[p*3+2] * R[6+e] + T[e];
      qh[32 + p*3 + e] = (f16)(SCALE * qg); q2 += qg * qg;
      kh[32 + p*3 + e] = (f16)kg;           k2 += kg * kg;
      vfT[((size_t)(h * 48 + 32 + p*3 + e)) * NRES + n] = (f16)vg;
    }
  }
  qh[44] = (f16)(-0.5f * SCALE * q2); qh[45] = (f16)1.f;
  kh[44] = (f16)1.f;                  kh[45] = (f16)(-0.5f * SCALE * k2);
#pragma unroll
  for (int c = 46; c < 64; ++c) { qh[c] = (f16)0.f; kh[c] = (f16)0.f; }
#pragma unroll
  for (int c = 44; c < 48; ++c) vfT[((size_t)(h * 48 + c)) * NRES + n] = (f16)0.f;
  f16* qo = qf + ((size_t)(h * NRES + n)) * 64;
  f16* ko = kf + ((size_t)(h * NRES + n)) * 64;
#pragma unroll
  for (int j = 0; j < 8; ++j) {
    *(f16x8*)&qo[j * 8] = *(const f16x8*)&qh[j * 8];
    *(f16x8*)&ko[j * 8] = *(const f16x8*)&kh[j * 8];
  }
}

// ---------------- K3: per-(head, q-tile) attention over full m-range ----------------
__global__ __launch_bounds__(512) void attn_full(
    const f16* __restrict__ biasb,
    const f16* __restrict__ qf, const f16* __restrict__ kf, const f16* __restrict__ vfT,
    f16* __restrict__ attn_cat) {
  __shared__ f16 bias_l[16 * 776];        // 16 q rows x 768 m, row stride 776
  __shared__ float redO[8][16][48];
  __shared__ float redD[8][16];
  const int t = threadIdx.x;
  const int w = t >> 6, l = t & 63;
  const int lg = l >> 4, lr = l & 15;
  const int h = blockIdx.x;
  const int q0 = blockIdx.y * 16;

  {
    const f16* src = biasb + (size_t)h * (NRES * NRES) + (size_t)q0 * NRES;
    for (int i = t; i < 16 * 96; i += 512) {
      int row = i / 96, c8 = i % 96;
      *(f16x8*)&bias_l[row * 776 + c8 * 8] = *(const f16x8*)(src + (size_t)row * NRES + c8 * 8);
    }
  }
  const f16* qrow = qf + ((size_t)(h * NRES + q0 + lr)) * 64;
  f16x8 qa0 = *(const f16x8*)(qrow + lg * 8);
  f16x8 qa1 = *(const f16x8*)(qrow + 32 + lg * 8);
  __syncthreads();

  float den[4] = {0.f, 0.f, 0.f, 0.f};
#pragma unroll
  for (int mc2 = 0; mc2 < 6; ++mc2) {
    const int mcol = w * 96 + mc2 * 16;
    const f16* krow = kf + ((size_t)(h * NRES + mcol + lr)) * 64;
    f16x8 kb0 = *(const f16x8*)(krow + lg * 8);
    f16x8 kb1 = *(const f16x8*)(krow + 32 + lg * 8);
    f32x4 s = {0.f, 0.f, 0.f, 0.f};
    s = __builtin_amdgcn_mfma_f32_16x16x32_f16(qa0, kb0, s, 0, 0, 0);
    s = __builtin_amdgcn_mfma_f32_16x16x32_f16(qa1, kb1, s, 0, 0, 0);
#pragma unroll
    for (int r = 0; r < 4; ++r) {
      const int pidx = (lg * 4 + r) * 776 + mcol + lr;
      float b = (float)bias_l[pidx];
      float e = __expf(s[r] + b);
      den[r] += e;
      bias_l[pidx] = (f16)e;
    }
  }
#pragma unroll
  for (int r = 0; r < 4; ++r) {
    float d = den[r];
    d += __shfl_xor(d, 1); d += __shfl_xor(d, 2);
    d += __shfl_xor(d, 4); d += __shfl_xor(d, 8);
    if (lr == 0) redD[w][lg * 4 + r] = d;
  }
  f32x4 a0 = {0.f,0.f,0.f,0.f}, a1 = {0.f,0.f,0.f,0.f}, a2 = {0.f,0.f,0.f,0.f};
#pragma unroll
  for (int ks = 0; ks < 3; ++ks) {
    const int mbase = w * 96 + ks * 32;
    f16x8 pa = *(const f16x8*)&bias_l[lr * 776 + mbase + lg * 8];
    const f16* vbase = vfT + ((size_t)(h * 48 + lr)) * NRES + mbase + lg * 8;
    f16x8 vb0 = *(const f16x8*)(vbase);
    f16x8 vb1 = *(const f16x8*)(vbase + 16 * NRES);
    f16x8 vb2 = *(const f16x8*)(vbase + 32 * NRES);
    a0 = __builtin_amdgcn_mfma_f32_16x16x32_f16(pa, vb0, a0, 0, 0, 0);
    a1 = __builtin_amdgcn_mfma_f32_16x16x32_f16(pa, vb1, a1, 0, 0, 0);
    a2 = __builtin_amdgcn_mfma_f32_16x16x32_f16(pa, vb2, a2, 0, 0, 0);
  }
#pragma unroll
  for (int r = 0; r < 4; ++r) {
    redO[w][lg * 4 + r][lr]      = a0[r];
    redO[w][lg * 4 + r][16 + lr] = a1[r];
    redO[w][lg * 4 + r][32 + lr] = a2[r];
  }
  __syncthreads();
  for (int o = t; o < 16 * 48; o += 512) {
    int q = o / 48, c = o % 48;
    float num = 0.f, ds = 0.f;
#pragma unroll
    for (int ww = 0; ww < 8; ++ww) { num += redO[ww][q][c]; ds += redD[ww][q]; }
    float val = num / ds;
    int n = q0 + q;
    if (c < 32)      attn_cat[(size_t)n * 576 + h * 32 + c] = (f16)val;
    else if (c < 44) attn_cat[(size_t)n * 576 + 384 + h * 12 + (c - 32)] = (f16)val;
  }
  if (h == 0) {
    for (int o = t; o < 16 * 48; o += 512) {
      int q = o / 48, c = o % 48;
      attn_cat[(size_t)(q0 + q) * 576 + 528 + c] = (f16)(c == 0 ? 1.f : 0.f);
    }
  }
}

// ---------------- layernorm ----------------
__global__ __launch_bounds__(64) void ln_kernel(
    const float* __restrict__ x, const float* __restrict__ w, const float* __restrict__ b,
    float* __restrict__ out) {
  int n = blockIdx.x;
  int l = threadIdx.x;
  const float* xr = x + (size_t)n * CDIM;
  float v[6];
  float s = 0.f;
#pragma unroll
  for (int i = 0; i < 6; ++i) { v[i] = xr[l + 64 * i]; s += v[i]; }
#pragma unroll
  for (int o = 32; o; o >>= 1) s += __shfl_xor(s, o);
  float mu = s * (1.f / 384.f);
  float vs = 0.f;
#pragma unroll
  for (int i = 0; i < 6; ++i) { float d = v[i] - mu; vs += d * d; }
#pragma unroll
  for (int o = 32; o; o >>= 1) vs += __shfl_xor(vs, o);
  float rstd = rsqrtf(vs * (1.f / 384.f) + 1e-5f);
  float* orow = out + (size_t)n * CDIM;
#pragma unroll
  for (int i = 0; i < 6; ++i) {
    int c = l + 64 * i;
    orow[c] = (v[i] - mu) * rstd * w[c] + b[c];
  }
}

extern "C" void kernel_launch(void* const* d_in, const int* in_sizes, int n_in,
                              void* d_out, int out_size, void* d_ws, size_t ws_size,
                              hipStream_t stream) {
  const float* single = (const float*)d_in[0];
  const float* pair   = (const float*)d_in[1];
  const float* rot    = (const float*)d_in[2];
  const float* trans  = (const float*)d_in[3];
  const float* Wq  = (const float*)d_in[4];
  const float* bq  = (const float*)d_in[5];
  const float* Wk  = (const float*)d_in[6];
  const float* bk  = (const float*)d_in[7];
  const float* Wv  = (const float*)d_in[8];
  const float* bv  = (const float*)d_in[9];
  const float* Wpb = (const float*)d_in[10];
  const float* bpb = (const float*)d_in[11];
  const float* Wqp = (const float*)d_in[12];
  const float* bqp = (const float*)d_in[13];
  const float* Wkp = (const float*)d_in[14];
  const float* bkp = (const float*)d_in[15];
  const float* Wvp = (const float*)d_in[16];
  const float* bvp = (const float*)d_in[17];
  const float* Wo  = (const float*)d_in[18];
  const float* bo  = (const float*)d_in[19];
  const float* Wpo = (const float*)d_in[20];
  const float* bpo = (const float*)d_in[21];
  const float* lnw = (const float*)d_in[22];
  const float* lnb = (const float*)d_in[23];

  float* ws = (float*)d_ws;
  f16* S16      = (f16*)ws; ws += 768 * 1584 / 2;
  f16* Wcomb    = (f16*)ws; ws += 384 * 192 / 2;
  f16* biasb    = (f16*)ws; ws += 12 * 768 * 768 / 2;
  f16* qf       = (f16*)ws; ws += 12 * 768 * 64 / 2;
  f16* kf       = (f16*)ws; ws += 12 * 768 * 64 / 2;
  f16* vfT      = (f16*)ws; ws += 12 * 48 * 768 / 2;
  f16* attn_cat = (f16*)ws; ws += 768 * 576 / 2;
  float* xb     = ws;       ws += 768 * 384;

  k1_mega<<<894, 512, 0, stream>>>(pair, Wpb, bpb, single,
                                   Wq, Wk, Wv, Wqp, Wkp, Wvp,
                                   bq, bk, bv, bqp, bkp, bvp,
                                   Wpo, bpo, Wo, biasb, Wcomb, S16);
  rot_feats3<<<dim3(12, 12), 64, 0, stream>>>(S16, rot, trans, qf, kf, vfT);
  attn_full<<<dim3(12, 48), 512, 0, stream>>>(biasb, qf, kf, vfT, attn_cat);
  final_gemm<<<dim3(6, 12), 256, 0, stream>>>(attn_cat, Wo, Wcomb, bo, single, xb);
  ln_kernel<<<768, 64, 0, stream>>>(xb, lnw, lnb, (float*)d_out);
}

// Round 16
// 113.560 us; speedup vs baseline: 1.0965x; 1.0965x over previous
//
#include <hip/hip_runtime.h>
#include <math.h>

#define NRES 768
#define CDIM 384
#define HEADS 12
#define SCALE 0.17677669529663687f  // 1/sqrt(32)

typedef _Float16 f16;
typedef _Float16 __attribute__((ext_vector_type(8))) f16x8;
typedef float __attribute__((ext_vector_type(4))) f32x4;

__device__ __forceinline__ f16x8 ldcvt8(const float* __restrict__ p) {
  float4 a = *(const float4*)p;
  float4 b = *(const float4*)(p + 4);
  f16x8 r = {(f16)a.x, (f16)a.y, (f16)a.z, (f16)a.w,
             (f16)b.x, (f16)b.y, (f16)b.z, (f16)b.w};
  return r;
}

// 4-wave (256-thr) MFMA step, used by final_gemm
__device__ __forceinline__ void mfma_step(f16 (*As)[64], f16 (*Bs)[64],
                                          int w, int lg, int lr, f32x4* acc) {
#pragma unroll
  for (int ks = 0; ks < 2; ++ks) {
    f16x8 af = *(const f16x8*)&As[w * 16 + lr][((ks * 4 + lg) ^ (lr & 7)) * 8];
#pragma unroll
    for (int c = 0; c < 4; ++c) {
      f16x8 bf = *(const f16x8*)&Bs[c * 16 + lr][((ks * 4 + lg) ^ (lr & 7)) * 8];
      acc[c] = __builtin_amdgcn_mfma_f32_16x16x32_f16(af, bf, acc[c], 0, 0, 0);
    }
  }
}

// ---------------- K1: role-split mega kernel (512 thr) ----------------
// bid<576:        pair-bias stream -> biasb[h][n][m] (fp16, 14 MB); loads hoisted per g8
// 576<=bid<876:   S16[768x1584] = f16(single * Wcat^T + bcat)
// 876<=bid<894:   Wcomb[384x192] = Wo * [Wpo | bpo | 0]^T
__global__ __launch_bounds__(512) void k1_mega(
    const float* __restrict__ pair, const float* __restrict__ Wpb, const float* __restrict__ bpb,
    const float* __restrict__ single,
    const float* __restrict__ Wq, const float* __restrict__ Wk, const float* __restrict__ Wv,
    const float* __restrict__ Wqp, const float* __restrict__ Wkp, const float* __restrict__ Wvp,
    const float* __restrict__ bq, const float* __restrict__ bk, const float* __restrict__ bv,
    const float* __restrict__ bqp, const float* __restrict__ bkp, const float* __restrict__ bvp,
    const float* __restrict__ Wpo, const float* __restrict__ bpo, const float* __restrict__ Wo,
    f16* __restrict__ biasb, f16* __restrict__ Wcomb, f16* __restrict__ S16) {
  __shared__ f16 smem[12 * 1160];   // 27.8 KB; aliased per role
  const int bid = blockIdx.x;
  const int t = threadIdx.x;
  const int w = t >> 6, l = t & 63;
  const int lg = l >> 4, lr = l & 15;
  const f16 z0 = (f16)0.f;

  if (bid < 576) {
    f16* bias_l = smem;             // [12][1160], row stride 72
    const int mblk = bid % 12;
    const int q0 = (bid / 12) * 16;
    const int m0 = mblk * 64;
    f16x8 bfr[4];
#pragma unroll
    for (int ks = 0; ks < 4; ++ks)
#pragma unroll
      for (int j = 0; j < 8; ++j)
        bfr[ks][j] = (f16)((lr < HEADS) ? Wpb[lr * 128 + ks * 32 + lg * 8 + j] : 0.f);
    const float bh = (lr < HEADS) ? bpb[lr] : 0.f;
#pragma unroll
    for (int g8 = 0; g8 < 8; ++g8) {
      const int g = w * 8 + g8;
      const int rowf = g * 16 + lr;
      const int nf = rowf >> 6, mf = rowf & 63;
      const float* ap = pair + (((size_t)(q0 + nf)) * NRES + (m0 + mf)) * 128 + lg * 8;
      // hoist all 8 loads for this iteration before the MFMA chain (ILP, G7)
      float4 x[8];
#pragma unroll
      for (int ks = 0; ks < 4; ++ks) {
        x[2 * ks]     = *(const float4*)(ap + ks * 32);
        x[2 * ks + 1] = *(const float4*)(ap + ks * 32 + 4);
      }
      f32x4 acc = {0.f, 0.f, 0.f, 0.f};
#pragma unroll
      for (int ks = 0; ks < 4; ++ks) {
        f16x8 af = {(f16)x[2*ks].x, (f16)x[2*ks].y, (f16)x[2*ks].z, (f16)x[2*ks].w,
                    (f16)x[2*ks+1].x, (f16)x[2*ks+1].y, (f16)x[2*ks+1].z, (f16)x[2*ks+1].w};
        acc = __builtin_amdgcn_mfma_f32_16x16x32_f16(af, bfr[ks], acc, 0, 0, 0);
      }
      if (lr < HEADS) {
#pragma unroll
        for (int r = 0; r < 4; ++r) {
          int rowo = g * 16 + lg * 4 + r;
          bias_l[lr * 1160 + (rowo >> 6) * 72 + (rowo & 63)] = (f16)(acc[r] + bh);
        }
      }
    }
    __syncthreads();
    for (int i = t; i < 12 * 16 * 8; i += 512) {
      int h = i >> 7;
      int rem = i & 127;
      int row = rem >> 3, c8 = rem & 7;
      *(f16x8*)(biasb + (size_t)h * (NRES * NRES) + (size_t)(q0 + row) * NRES + m0 + c8 * 8) =
          *(const f16x8*)&smem[h * 1160 + row * 72 + c8 * 8];
    }
    return;
  }

  f16 (*As)[64] = (f16(*)[64])smem;
  f16 (*Bs)[64] = (f16(*)[64])(smem + 4096);
  const int wm = w & 3, wn = w >> 2;
  f32x4 acc[2] = {{0.f,0.f,0.f,0.f},{0.f,0.f,0.f,0.f}};

  if (bid < 876) {
    const int i = bid - 576;
    const int bm = (i / 25) * 64, bn = (i % 25) * 64;
    for (int k0 = 0; k0 < 384; k0 += 64) {
      __syncthreads();
      {
        int row = t >> 3, k8 = t & 7;
        int sw = (k8 ^ (row & 7)) * 8;
        *(f16x8*)&As[row][sw] = ldcvt8(single + (size_t)(bm + row) * 384 + k0 + k8 * 8);
        int o = bn + row;
        const float* bsrc;
        if (o < 384)       bsrc = Wq  + (size_t)o * 384;
        else if (o < 768)  bsrc = Wk  + (size_t)(o - 384) * 384;
        else if (o < 1152) bsrc = Wv  + (size_t)(o - 768) * 384;
        else if (o < 1296) bsrc = Wqp + (size_t)(o - 1152) * 384;
        else if (o < 1440) bsrc = Wkp + (size_t)(o - 1296) * 384;
        else if (o < 1584) bsrc = Wvp + (size_t)(o - 1440) * 384;
        else               bsrc = nullptr;
        f16x8 vb8 = {z0, z0, z0, z0, z0, z0, z0, z0};
        if (bsrc) vb8 = ldcvt8(bsrc + k0 + k8 * 8);
        *(f16x8*)&Bs[row][sw] = vb8;
      }
      __syncthreads();
#pragma unroll
      for (int ks = 0; ks < 2; ++ks) {
        f16x8 af = *(const f16x8*)&As[wm * 16 + lr][((ks * 4 + lg) ^ (lr & 7)) * 8];
#pragma unroll
        for (int j = 0; j < 2; ++j) {
          f16x8 bf = *(const f16x8*)&Bs[(wn * 2 + j) * 16 + lr][((ks * 4 + lg) ^ (lr & 7)) * 8];
          acc[j] = __builtin_amdgcn_mfma_f32_16x16x32_f16(af, bf, acc[j], 0, 0, 0);
        }
      }
    }
#pragma unroll
    for (int j = 0; j < 2; ++j) {
      int col = bn + (wn * 2 + j) * 16 + lr;
      if (col >= 1584) continue;
      float bb;
      if (col < 384)       bb = bq[col];
      else if (col < 768)  bb = bk[col - 384];
      else if (col < 1152) bb = bv[col - 768];
      else if (col < 1296) bb = bqp[col - 1152];
      else if (col < 1440) bb = bkp[col - 1296];
      else                 bb = bvp[col - 1440];
#pragma unroll
      for (int r = 0; r < 4; ++r) {
        int row = bm + wm * 16 + lg * 4 + r;
        S16[(size_t)row * 1584 + col] = (f16)(acc[j][r] + bb);
      }
    }
  } else {
    const int i = bid - 876;
    const int bm = (i / 3) * 64, bn = (i % 3) * 64;
    for (int k0 = 0; k0 < 384; k0 += 64) {
      __syncthreads();
      {
        int row = t >> 3, k8 = t & 7;
        int sw = (k8 ^ (row & 7)) * 8;
        *(f16x8*)&As[row][sw] = ldcvt8(Wo + (size_t)(bm + row) * 384 + k0 + k8 * 8);
        int pr = bn + row;
        f16x8 vb8 = {z0, z0, z0, z0, z0, z0, z0, z0};
        if (pr < 144) {
#pragma unroll
          for (int j = 0; j < 8; ++j) vb8[j] = (f16)Wpo[(size_t)(k0 + k8 * 8 + j) * 144 + pr];
        } else if (pr == 144) {
#pragma unroll
          for (int j = 0; j < 8; ++j) vb8[j] = (f16)bpo[k0 + k8 * 8 + j];
        }
        *(f16x8*)&Bs[row][sw] = vb8;
      }
      __syncthreads();
#pragma unroll
      for (int ks = 0; ks < 2; ++ks) {
        f16x8 af = *(const f16x8*)&As[wm * 16 + lr][((ks * 4 + lg) ^ (lr & 7)) * 8];
#pragma unroll
        for (int j = 0; j < 2; ++j) {
          f16x8 bf = *(const f16x8*)&Bs[(wn * 2 + j) * 16 + lr][((ks * 4 + lg) ^ (lr & 7)) * 8];
          acc[j] = __builtin_amdgcn_mfma_f32_16x16x32_f16(af, bf, acc[j], 0, 0, 0);
        }
      }
    }
#pragma unroll
    for (int j = 0; j < 2; ++j) {
      int col = bn + (wn * 2 + j) * 16 + lr;
      if (col >= 192) continue;
#pragma unroll
      for (int r = 0; r < 4; ++r)
        Wcomb[(size_t)(bm + wm * 16 + lg * 4 + r) * 192 + col] = (f16)acc[j][r];
    }
  }
}

// ---------------- final output GEMM: xb = attn_cat * [Wo | Wcomb]^T + bo + single ----------------
__global__ __launch_bounds__(256) void final_gemm(
    const f16* __restrict__ attn_cat, const float* __restrict__ Wo,
    const f16* __restrict__ Wcomb, const float* __restrict__ bo,
    const float* __restrict__ single, float* __restrict__ xb) {
  __shared__ f16 As[64][64];
  __shared__ f16 Bs[64][64];
  const int t = threadIdx.x;
  const int w = t >> 6, l = t & 63;
  const int lg = l >> 4, lr = l & 15;
  const int bm = blockIdx.y * 64, bn = blockIdx.x * 64;
  f32x4 acc[4] = {{0.f,0.f,0.f,0.f},{0.f,0.f,0.f,0.f},{0.f,0.f,0.f,0.f},{0.f,0.f,0.f,0.f}};
  for (int k0 = 0; k0 < 576; k0 += 64) {
    __syncthreads();
#pragma unroll
    for (int cc = 0; cc < 2; ++cc) {
      int c = t + cc * 256;
      int row = c >> 3, k8 = c & 7;
      int sw = (k8 ^ (row & 7)) * 8;
      *(f16x8*)&As[row][sw] = *(const f16x8*)(attn_cat + (size_t)(bm + row) * 576 + k0 + k8 * 8);
      f16x8 vb8;
      if (k0 < 384) vb8 = ldcvt8(Wo + (size_t)(bn + row) * 384 + k0 + k8 * 8);
      else          vb8 = *(const f16x8*)(Wcomb + (size_t)(bn + row) * 192 + (k0 - 384) + k8 * 8);
      *(f16x8*)&Bs[row][sw] = vb8;
    }
    __syncthreads();
    mfma_step(As, Bs, w, lg, lr, acc);
  }
#pragma unroll
  for (int c = 0; c < 4; ++c) {
    int col = bn + c * 16 + lr;
    float bb = bo[col];
#pragma unroll
    for (int r = 0; r < 4; ++r) {
      int row = bm + w * 16 + lg * 4 + r;
      xb[(size_t)row * 384 + col] = acc[c][r] + bb + single[(size_t)row * 384 + col];
    }
  }
}

// ---------------- rotate points, build packed fp16 features ----------------
__global__ __launch_bounds__(64) void rot_feats3(
    const f16* __restrict__ S16, const float* __restrict__ rot, const float* __restrict__ trans,
    f16* __restrict__ qf, f16* __restrict__ kf, f16* __restrict__ vfT) {
  const int n = blockIdx.x * 64 + threadIdx.x;
  const int h = blockIdx.y;
  const f16* Sr = S16 + (size_t)n * 1584;
  float R[9], T[3];
#pragma unroll
  for (int i = 0; i < 9; ++i) R[i] = rot[n * 9 + i];
#pragma unroll
  for (int i = 0; i < 3; ++i) T[i] = trans[n * 3 + i];
  f16 qh[64], kh[64];
  f16x8 qv4[4], kv4[4], vv4[4];
#pragma unroll
  for (int j = 0; j < 4; ++j) {
    qv4[j] = *(const f16x8*)(Sr + h * 32 + j * 8);
    kv4[j] = *(const f16x8*)(Sr + 384 + h * 32 + j * 8);
    vv4[j] = *(const f16x8*)(Sr + 768 + h * 32 + j * 8);
  }
#pragma unroll
  for (int c = 0; c < 32; ++c) {
    qh[c] = (f16)(SCALE * (float)qv4[c >> 3][c & 7]);
    vfT[((size_t)(h * 48 + c)) * NRES + n] = vv4[c >> 3][c & 7];
  }
#pragma unroll
  for (int j = 0; j < 4; ++j) *(f16x8*)&kh[j * 8] = kv4[j];
  float qp[12], kp[12], vp[12];
#pragma unroll
  for (int e = 0; e < 12; ++e) {
    qp[e] = (float)Sr[1152 + h * 12 + e];
    kp[e] = (float)Sr[1296 + h * 12 + e];
    vp[e] = (float)Sr[1440 + h * 12 + e];
  }
  float q2 = 0.f, k2 = 0.f;
#pragma unroll
  for (int p = 0; p < 4; ++p) {
#pragma unroll
    for (int e = 0; e < 3; ++e) {
      float qg = qp[p*3+0] * R[e] + qp[p*3+1] * R[3+e] + qp[p*3+2] * R[6+e] + T[e];
      float kg = kp[p*3+0] * R[e] + kp[p*3+1] * R[3+e] + kp[p*3+2] * R[6+e] + T[e];
      float vg = vp[p*3+0] * R[e] + vp[p*3+1] * R[3+e] + vp[p*3+2] * R[6+e] + T[e];
      qh[32 + p*3 + e] = (f16)(SCALE * qg); q2 += qg * qg;
      kh[32 + p*3 + e] = (f16)kg;           k2 += kg * kg;
      vfT[((size_t)(h * 48 + 32 + p*3 + e)) * NRES + n] = (f16)vg;
    }
  }
  qh[44] = (f16)(-0.5f * SCALE * q2); qh[45] = (f16)1.f;
  kh[44] = (f16)1.f;                  kh[45] = (f16)(-0.5f * SCALE * k2);
#pragma unroll
  for (int c = 46; c < 64; ++c) { qh[c] = (f16)0.f; kh[c] = (f16)0.f; }
#pragma unroll
  for (int c = 44; c < 48; ++c) vfT[((size_t)(h * 48 + c)) * NRES + n] = (f16)0.f;
  f16* qo = qf + ((size_t)(h * NRES + n)) * 64;
  f16* ko = kf + ((size_t)(h * NRES + n)) * 64;
#pragma unroll
  for (int j = 0; j < 8; ++j) {
    *(f16x8*)&qo[j * 8] = *(const f16x8*)&qh[j * 8];
    *(f16x8*)&ko[j * 8] = *(const f16x8*)&kh[j * 8];
  }
}

// ---------------- K3: per-(head, q-tile) attention over full m-range ----------------
__global__ __launch_bounds__(512) void attn_full(
    const f16* __restrict__ biasb,
    const f16* __restrict__ qf, const f16* __restrict__ kf, const f16* __restrict__ vfT,
    f16* __restrict__ attn_cat) {
  __shared__ f16 bias_l[16 * 776];        // 16 q rows x 768 m, row stride 776
  __shared__ float redO[8][16][48];
  __shared__ float redD[8][16];
  const int t = threadIdx.x;
  const int w = t >> 6, l = t & 63;
  const int lg = l >> 4, lr = l & 15;
  const int h = blockIdx.x;
  const int q0 = blockIdx.y * 16;

  {
    const f16* src = biasb + (size_t)h * (NRES * NRES) + (size_t)q0 * NRES;
    for (int i = t; i < 16 * 96; i += 512) {
      int row = i / 96, c8 = i % 96;
      *(f16x8*)&bias_l[row * 776 + c8 * 8] = *(const f16x8*)(src + (size_t)row * NRES + c8 * 8);
    }
  }
  const f16* qrow = qf + ((size_t)(h * NRES + q0 + lr)) * 64;
  f16x8 qa0 = *(const f16x8*)(qrow + lg * 8);
  f16x8 qa1 = *(const f16x8*)(qrow + 32 + lg * 8);
  __syncthreads();

  float den[4] = {0.f, 0.f, 0.f, 0.f};
#pragma unroll
  for (int mc2 = 0; mc2 < 6; ++mc2) {
    const int mcol = w * 96 + mc2 * 16;
    const f16* krow = kf + ((size_t)(h * NRES + mcol + lr)) * 64;
    f16x8 kb0 = *(const f16x8*)(krow + lg * 8);
    f16x8 kb1 = *(const f16x8*)(krow + 32 + lg * 8);
    f32x4 s = {0.f, 0.f, 0.f, 0.f};
    s = __builtin_amdgcn_mfma_f32_16x16x32_f16(qa0, kb0, s, 0, 0, 0);
    s = __builtin_amdgcn_mfma_f32_16x16x32_f16(qa1, kb1, s, 0, 0, 0);
#pragma unroll
    for (int r = 0; r < 4; ++r) {
      const int pidx = (lg * 4 + r) * 776 + mcol + lr;
      float b = (float)bias_l[pidx];
      float e = __expf(s[r] + b);
      den[r] += e;
      bias_l[pidx] = (f16)e;
    }
  }
#pragma unroll
  for (int r = 0; r < 4; ++r) {
    float d = den[r];
    d += __shfl_xor(d, 1); d += __shfl_xor(d, 2);
    d += __shfl_xor(d, 4); d += __shfl_xor(d, 8);
    if (lr == 0) redD[w][lg * 4 + r] = d;
  }
  f32x4 a0 = {0.f,0.f,0.f,0.f}, a1 = {0.f,0.f,0.f,0.f}, a2 = {0.f,0.f,0.f,0.f};
#pragma unroll
  for (int ks = 0; ks < 3; ++ks) {
    const int mbase = w * 96 + ks * 32;
    f16x8 pa = *(const f16x8*)&bias_l[lr * 776 + mbase + lg * 8];
    const f16* vbase = vfT + ((size_t)(h * 48 + lr)) * NRES + mbase + lg * 8;
    f16x8 vb0 = *(const f16x8*)(vbase);
    f16x8 vb1 = *(const f16x8*)(vbase + 16 * NRES);
    f16x8 vb2 = *(const f16x8*)(vbase + 32 * NRES);
    a0 = __builtin_amdgcn_mfma_f32_16x16x32_f16(pa, vb0, a0, 0, 0, 0);
    a1 = __builtin_amdgcn_mfma_f32_16x16x32_f16(pa, vb1, a1, 0, 0, 0);
    a2 = __builtin_amdgcn_mfma_f32_16x16x32_f16(pa, vb2, a2, 0, 0, 0);
  }
#pragma unroll
  for (int r = 0; r < 4; ++r) {
    redO[w][lg * 4 + r][lr]      = a0[r];
    redO[w][lg * 4 + r][16 + lr] = a1[r];
    redO[w][lg * 4 + r][32 + lr] = a2[r];
  }
  __syncthreads();
  for (int o = t; o < 16 * 48; o += 512) {
    int q = o / 48, c = o % 48;
    float num = 0.f, ds = 0.f;
#pragma unroll
    for (int ww = 0; ww < 8; ++ww) { num += redO[ww][q][c]; ds += redD[ww][q]; }
    float val = num / ds;
    int n = q0 + q;
    if (c < 32)      attn_cat[(size_t)n * 576 + h * 32 + c] = (f16)val;
    else if (c < 44) attn_cat[(size_t)n * 576 + 384 + h * 12 + (c - 32)] = (f16)val;
  }
  if (h == 0) {
    for (int o = t; o < 16 * 48; o += 512) {
      int q = o / 48, c = o % 48;
      attn_cat[(size_t)(q0 + q) * 576 + 528 + c] = (f16)(c == 0 ? 1.f : 0.f);
    }
  }
}

// ---------------- layernorm ----------------
__global__ __launch_bounds__(64) void ln_kernel(
    const float* __restrict__ x, const float* __restrict__ w, const float* __restrict__ b,
    float* __restrict__ out) {
  int n = blockIdx.x;
  int l = threadIdx.x;
  const float* xr = x + (size_t)n * CDIM;
  float v[6];
  float s = 0.f;
#pragma unroll
  for (int i = 0; i < 6; ++i) { v[i] = xr[l + 64 * i]; s += v[i]; }
#pragma unroll
  for (int o = 32; o; o >>= 1) s += __shfl_xor(s, o);
  float mu = s * (1.f / 384.f);
  float vs = 0.f;
#pragma unroll
  for (int i = 0; i < 6; ++i) { float d = v[i] - mu; vs += d * d; }
#pragma unroll
  for (int o = 32; o; o >>= 1) vs += __shfl_xor(vs, o);
  float rstd = rsqrtf(vs * (1.f / 384.f) + 1e-5f);
  float* orow = out + (size_t)n * CDIM;
#pragma unroll
  for (int i = 0; i < 6; ++i) {
    int c = l + 64 * i;
    orow[c] = (v[i] - mu) * rstd * w[c] + b[c];
  }
}

extern "C" void kernel_launch(void* const* d_in, const int* in_sizes, int n_in,
                              void* d_out, int out_size, void* d_ws, size_t ws_size,
                              hipStream_t stream) {
  const float* single = (const float*)d_in[0];
  const float* pair   = (const float*)d_in[1];
  const float* rot    = (const float*)d_in[2];
  const float* trans  = (const float*)d_in[3];
  const float* Wq  = (const float*)d_in[4];
  const float* bq  = (const float*)d_in[5];
  const float* Wk  = (const float*)d_in[6];
  const float* bk  = (const float*)d_in[7];
  const float* Wv  = (const float*)d_in[8];
  const float* bv  = (const float*)d_in[9];
  const float* Wpb = (const float*)d_in[10];
  const float* bpb = (const float*)d_in[11];
  const float* Wqp = (const float*)d_in[12];
  const float* bqp = (const float*)d_in[13];
  const float* Wkp = (const float*)d_in[14];
  const float* bkp = (const float*)d_in[15];
  const float* Wvp = (const float*)d_in[16];
  const float* bvp = (const float*)d_in[17];
  const float* Wo  = (const float*)d_in[18];
  const float* bo  = (const float*)d_in[19];
  const float* Wpo = (const float*)d_in[20];
  const float* bpo = (const float*)d_in[21];
  const float* lnw = (const float*)d_in[22];
  const float* lnb = (const float*)d_in[23];

  float* ws = (float*)d_ws;
  f16* S16      = (f16*)ws; ws += 768 * 1584 / 2;
  f16* Wcomb    = (f16*)ws; ws += 384 * 192 / 2;
  f16* biasb    = (f16*)ws; ws += 12 * 768 * 768 / 2;
  f16* qf       = (f16*)ws; ws += 12 * 768 * 64 / 2;
  f16* kf       = (f16*)ws; ws += 12 * 768 * 64 / 2;
  f16* vfT      = (f16*)ws; ws += 12 * 48 * 768 / 2;
  f16* attn_cat = (f16*)ws; ws += 768 * 576 / 2;
  float* xb     = ws;       ws += 768 * 384;

  k1_mega<<<894, 512, 0, stream>>>(pair, Wpb, bpb, single,
                                   Wq, Wk, Wv, Wqp, Wkp, Wvp,
                                   bq, bk, bv, bqp, bkp, bvp,
                                   Wpo, bpo, Wo, biasb, Wcomb, S16);
  rot_feats3<<<dim3(12, 12), 64, 0, stream>>>(S16, rot, trans, qf, kf, vfT);
  attn_full<<<dim3(12, 48), 512, 0, stream>>>(biasb, qf, kf, vfT, attn_cat);
  final_gemm<<<dim3(6, 12), 256, 0, stream>>>(attn_cat, Wo, Wcomb, bo, single, xb);
  ln_kernel<<<768, 64, 0, stream>>>(xb, lnw, lnb, (float*)d_out);
}